// Round 2
// baseline (805.747 us; speedup 1.0000x reference)
//
#include <hip/hip_runtime.h>
#include <cstddef>

#define BB   256    // batch = GEMM1 M
#define UU   8      // in_units
#define ISZ  1152   // in_size
#define JJ   10     // out_units
#define DD   16     // out_size
#define JD   (JJ*DD)      // 160
#define K1   (UU*ISZ)     // 9216 ; sgemm k-order: k = i*8+u
#define ICH  16           // i per sgemm block
#define NIC  (ISZ/ICH)    // 72  (split-K part count)
#define NJH  5            // j-pairs
#define GRID (NIC*NJH)    // 360 blocks: 2/CU resident (LDS 66.6KB, VGPR<=256) -> 512 slots

typedef short v8s __attribute__((ext_vector_type(8)));   // 8 bf16 in 4 VGPRs
typedef float f4v __attribute__((ext_vector_type(4)));   // mfma accumulator
typedef unsigned short ush;

__device__ __forceinline__ ush f2bf(float f) {
    unsigned int u = __float_as_uint(f);
    unsigned int r = (u + 0x7fffu + ((u >> 16) & 1u)) >> 16;   // RNE
    return (ush)r;
}
__device__ __forceinline__ float bf2f(ush h) {
    return __uint_as_float(((unsigned int)h) << 16);
}

// device-scope grid barrier: one fresh counter per instance (memset to 0 on stream).
// release-add publishes this block's stores (L2 writeback); acquire-poll invalidates
// caches so post-barrier reads see remote XCDs' data. All blocks co-resident by
// construction (see GRID comment), so spinning cannot deadlock.
__device__ __forceinline__ void gbar(unsigned* c) {
    __syncthreads();
    if (threadIdx.x == 0) {
        __hip_atomic_fetch_add(c, 1u, __ATOMIC_RELEASE, __HIP_MEMORY_SCOPE_AGENT);
        while (__hip_atomic_load(c, __ATOMIC_ACQUIRE, __HIP_MEMORY_SCOPE_AGENT) < GRID) {
            __builtin_amdgcn_s_sleep(1);
        }
    }
    __syncthreads();
}

// One persistent kernel: prep -> 3x { sgemm -> reduce+squash -> mgemm }
// replaces 9 launches (8 device drain/ramp boundaries) with 8 in-kernel barriers.
__global__ __launch_bounds__(256, 2) void capsule_fused(
        const float* __restrict__ x, const float* __restrict__ W,
        float* __restrict__ v_out, float* __restrict__ ws) {
    // workspace layout: [0..63] barrier counters (+pad), then data
    unsigned* bar = (unsigned*)ws;                             // 8 used, 64 f reserved
    float* b_ij   = ws + 64;                                   // 11,520 f
    float* s_part = b_ij + ISZ * JJ;                           // 72*256*160 f
    ush* xsh = (ush*)(s_part + (size_t)NIC * BB * JD);         // [1152][2048]
    ush* xsl = xsh + (size_t)ISZ * 2048;
    ush* xth = xsl + (size_t)ISZ * 2048;                       // [9216][256]
    ush* xtl = xth + (size_t)K1 * BB;
    ush* vth = xtl + (size_t)K1 * BB;                          // [160][256]
    ush* vtl = vth + (size_t)JD * BB;

    const int bid  = blockIdx.x;
    const int t    = threadIdx.x;
    const int lane = t & 63, wv = t >> 6;
    const int col  = lane & 15, q = lane >> 4;

    // shared scratch, phase-aliased. max = prep's 32*8*65 floats = 66,560 B
    __shared__ __align__(16) char smem[66560];

    // ---------------- phase P: x[b,u,i] -> xs[i][b*8+u] + xt[u*1152+i][b]; b_ij=1 ----
    if (bid < 144) {
        float (*buf)[8][65] = (float (*)[8][65])smem;   // [32][8][65]
        int pit = bid % 18, bt = bid / 18;
        int i0 = pit * 64, b0 = bt * 32;
        int flat = bt * 18 + pit;
        if (flat < 45) b_ij[flat * 256 + t] = 1.0f;     // 45*256 = 11520

        for (int rep = 0; rep < 64; ++rep) {
            int row = rep * 4 + wv;                     // 0..255 = (bl,u)
            int bl = row >> 3, u = row & 7;
            buf[bl][u][lane] = x[(size_t)(b0 + bl) * K1 + (size_t)u * ISZ + i0 + lane];
        }
        __syncthreads();
        {   // xs[i][b*8+u]
            int bl = t >> 3, u = t & 7;
            for (int il = 0; il < 64; ++il) {
                float vv = buf[bl][u][il];
                ush h = f2bf(vv);
                size_t o = (size_t)(i0 + il) * 2048 + (size_t)(b0 + bl) * 8 + u;
                xsh[o] = h; xsl[o] = f2bf(vv - bf2f(h));
            }
        }
        {   // xt[u*1152+i][b]
            int g = t >> 5, bl = t & 31;
            for (int pass = 0; pass < 64; ++pass) {
                int cu = pass * 8 + g;
                int u = cu >> 6, il = cu & 63;
                float vv = buf[bl][u][il];
                ush h = f2bf(vv);
                size_t o = (size_t)(u * ISZ + i0 + il) * BB + b0 + bl;
                xth[o] = h; xtl[o] = f2bf(vv - bf2f(h));
            }
        }
    }
    gbar(&bar[0]);

    for (int it = 0; it < 3; ++it) {
        // ---------------- phase S: sgemm, block = (ic, jh) ----------------
        // bid = jh*72 + ic: the 5 blocks sharing an A-slice (same ic) are 72 apart
        // -> same XCD under round-robin -> A-slice L2-shared.
        {
            int ic = bid % NIC, jh = bid / NIC;
            int j0 = jh * 2, i0 = ic * ICH;

            ush (*bh_)[16][136] = (ush (*)[16][136])smem;            // [2][16][136] hi
            ush (*bl_)[16][136] = (ush (*)[16][136])(smem + 8704);   // lo
            float* c_lds = (float*)(smem + 17408);                   // [2][16]
            float* redm  = (float*)(smem + 17536);                   // [4]
            float* reds  = (float*)(smem + 17552);                   // [4]

            if (it == 0) {
                if (t < 2 * ICH) c_lds[t] = 1.0f / 1152.0f;
            } else {
                // parallel softmax: waves 0-1 -> jj=0, waves 2-3 -> jj=1
                int jj = wv >> 1, half = wv & 1;
                const float* bp = b_ij + (size_t)(j0 + jj) * ISZ;
                float m = -1e30f;
                for (int k = half * 64 + lane; k < ISZ; k += 128) m = fmaxf(m, bp[k]);
#pragma unroll
                for (int off = 32; off; off >>= 1) m = fmaxf(m, __shfl_down(m, off, 64));
                if (lane == 0) redm[wv] = m;
                __syncthreads();
                m = fmaxf(redm[jj * 2], redm[jj * 2 + 1]);
                float ssum = 0.f;
                for (int k = half * 64 + lane; k < ISZ; k += 128) ssum += __expf(bp[k] - m);
#pragma unroll
                for (int off = 32; off; off >>= 1) ssum += __shfl_down(ssum, off, 64);
                if (lane == 0) reds[wv] = ssum;
                __syncthreads();
                if (t < 2 * ICH) {
                    int cj = t >> 4, ci = t & 15;
                    float mj  = fmaxf(redm[cj * 2], redm[cj * 2 + 1]);
                    float inv = 1.f / (reds[cj * 2] + reds[cj * 2 + 1]);
                    c_lds[t] = __expf(b_ij[(size_t)(j0 + cj) * ISZ + i0 + ci] - mj) * inv;
                }
            }
            __syncthreads();

            // build B tiles: 512 slots = (jj, ii, d), 2 per thread
            for (int slot = t; slot < 512; slot += 256) {
                int jj = slot >> 8, rem = slot & 255, ii = rem >> 4, d = rem & 15;
                const float* wp = W + (size_t)(i0 + ii) * 1280 + (j0 + jj) * 128 + d * 8;
                float4 wa = *(const float4*)wp;
                float4 wb = *(const float4*)(wp + 4);
                float ci = c_lds[jj * 16 + ii];
                float vals[8] = { wa.x * ci, wa.y * ci, wa.z * ci, wa.w * ci,
                                  wb.x * ci, wb.y * ci, wb.z * ci, wb.w * ci };
                v8s hv, lv;
#pragma unroll
                for (int u = 0; u < 8; ++u) {
                    ush h = f2bf(vals[u]);
                    hv[u] = (short)h;
                    lv[u] = (short)f2bf(vals[u] - bf2f(h));
                }
                *(v8s*)&bh_[jj][d][ii * 8] = hv;
                *(v8s*)&bl_[jj][d][ii * 8] = lv;
            }
            __syncthreads();

            int m_base = wv * 64;
            f4v acc[4][2];
#pragma unroll
            for (int mm = 0; mm < 4; ++mm)
#pragma unroll
                for (int jj = 0; jj < 2; ++jj) acc[mm][jj] = (f4v){0.f, 0.f, 0.f, 0.f};

#pragma unroll
            for (int s = 0; s < 4; ++s) {           // 4 k-steps x 32 k = 128 k (16 i)
                v8s bh0 = *(const v8s*)&bh_[0][col][s * 32 + q * 8];
                v8s bl0 = *(const v8s*)&bl_[0][col][s * 32 + q * 8];
                v8s bh1 = *(const v8s*)&bh_[1][col][s * 32 + q * 8];
                v8s bl1 = *(const v8s*)&bl_[1][col][s * 32 + q * 8];
                size_t abase = (size_t)(i0 + s * 4 + q) * 2048;
#pragma unroll
                for (int mm = 0; mm < 4; ++mm) {
                    size_t ao = abase + (size_t)(m_base + mm * 16 + col) * 8;
                    v8s ah = *(const v8s*)(xsh + ao);
                    v8s al = *(const v8s*)(xsl + ao);
                    acc[mm][0] = __builtin_amdgcn_mfma_f32_16x16x32_bf16(ah, bh0, acc[mm][0], 0, 0, 0);
                    acc[mm][0] = __builtin_amdgcn_mfma_f32_16x16x32_bf16(ah, bl0, acc[mm][0], 0, 0, 0);
                    acc[mm][0] = __builtin_amdgcn_mfma_f32_16x16x32_bf16(al, bh0, acc[mm][0], 0, 0, 0);
                    acc[mm][1] = __builtin_amdgcn_mfma_f32_16x16x32_bf16(ah, bh1, acc[mm][1], 0, 0, 0);
                    acc[mm][1] = __builtin_amdgcn_mfma_f32_16x16x32_bf16(ah, bl1, acc[mm][1], 0, 0, 0);
                    acc[mm][1] = __builtin_amdgcn_mfma_f32_16x16x32_bf16(al, bh1, acc[mm][1], 0, 0, 0);
                }
            }
            // C/D: col = n, row = q*4+r (= b within m-tile)  [R7-verified]
#pragma unroll
            for (int mm = 0; mm < 4; ++mm)
#pragma unroll
                for (int jj = 0; jj < 2; ++jj)
#pragma unroll
                    for (int r = 0; r < 4; ++r)
                        s_part[((size_t)ic * BB + m_base + mm * 16 + q * 4 + r) * JD
                               + (j0 + jj) * DD + col] = acc[mm][jj][r];
        }
        gbar(&bar[1 + it * 3]);

        // ---------------- phase R: reduce split-K + squash ----------------
        if (bid < BB) {
            int b = bid;
            float* sm = (float*)smem;   // [JD]
            if (t < JD) {
                float s = 0.f;
#pragma unroll 8
                for (int p = 0; p < NIC; ++p) s += s_part[((size_t)p * BB + b) * JD + t];
                sm[t] = s;
            }
            __syncthreads();
            if (t < JD) {
                int d = t & 15;
                float msq = 0.f;
#pragma unroll
                for (int j = 0; j < JJ; ++j) { float xx = sm[j * DD + d]; msq += xx * xx; }
                float val = msq / (1.f + msq) * sm[t] * rsqrtf(msq);
                if (it == 2) {
                    v_out[(size_t)b * JD + t] = val;     // final output only
                } else {
                    ush h = f2bf(val);
                    vth[(size_t)t * BB + b] = h;
                    vtl[(size_t)t * BB + b] = f2bf(val - bf2f(h));
                }
            }
        }
        if (it == 2) return;   // uniform across the whole grid
        gbar(&bar[2 + it * 3]);

        // ---------------- phase M: mgemm + agreement epilogue [R7-verified] ----------
        {
            int wbase = bid * 4 + wv;       // 0..1439; 5760 wave-jobs -> 4 reps
#pragma unroll
            for (int rep = 0; rep < 4; ++rep) {
                int wj = wbase + rep * 1440;
                int mt = wj / 576, nt = wj % 576;
                int m0 = mt * 16, n0 = nt * 16;
                size_t aoff = (size_t)(m0 + col) * BB + q * 8;
                size_t boff = (size_t)(n0 + col) * BB + q * 8;
                f4v acc = {0.f, 0.f, 0.f, 0.f};
#pragma unroll
                for (int s = 0; s < BB / 32; ++s) {
                    v8s ah = *(const v8s*)(vth + aoff);
                    v8s al = *(const v8s*)(vtl + aoff);
                    v8s bh = *(const v8s*)(xth + boff);
                    v8s bl = *(const v8s*)(xtl + boff);
                    acc = __builtin_amdgcn_mfma_f32_16x16x32_bf16(ah, bh, acc, 0, 0, 0);
                    acc = __builtin_amdgcn_mfma_f32_16x16x32_bf16(ah, bl, acc, 0, 0, 0);
                    acc = __builtin_amdgcn_mfma_f32_16x16x32_bf16(al, bh, acc, 0, 0, 0);
                    aoff += 32; boff += 32;
                }
                int u = nt / 72;
                int i = (nt % 72) * 16 + col;
                const float* Wp = W + (size_t)i * 1280 + mt * 128 + q * 32 + u;
                float p = Wp[0] * acc[0] + Wp[8] * acc[1] + Wp[16] * acc[2] + Wp[24] * acc[3];
                p += __shfl_xor(p, 16, 64);
                p += __shfl_xor(p, 32, 64);
                if (q == 0) atomicAdd(&b_ij[(size_t)mt * ISZ + i], p * (1.0f / 256.0f));
            }
        }
        gbar(&bar[3 + it * 3]);
    }
}

extern "C" void kernel_launch(void* const* d_in, const int* in_sizes, int n_in,
                              void* d_out, int out_size, void* d_ws, size_t ws_size,
                              hipStream_t stream) {
    const float* x = (const float*)d_in[0];   // (256, 8, 1152)
    const float* W = (const float*)d_in[1];   // (1, 1152, 10, 16, 8)
    float* v_out = (float*)d_out;             // (256, 10, 16, 1)
    float* ws = (float*)d_ws;

    // zero the barrier counters (stream-ordered, graph-capture-safe)
    hipMemsetAsync(ws, 0, 64 * sizeof(float), stream);
    hipLaunchKernelGGL(capsule_fused, dim3(GRID), dim3(256), 0, stream,
                       x, W, v_out, ws);
}

// Round 3
// 540.740 us; speedup vs baseline: 1.4901x; 1.4901x over previous
//
#include <hip/hip_runtime.h>
#include <cstddef>

#define BB   256    // batch = GEMM1 M
#define UU   8      // in_units
#define ISZ  1152   // in_size
#define JJ   10     // out_units
#define DD   16     // out_size
#define JD   (JJ*DD)      // 160
#define K1   (UU*ISZ)     // 9216 ; sgemm k-order: k = i*8+u
#define ICH  16           // i per sgemm block
#define NIC  (ISZ/ICH)    // 72  (split-K part count)
#define NJH  5            // j-pairs
#define GRID (NIC*NJH)    // 360 blocks: 2/CU resident (LDS 66.6KB, VGPR<=256) -> 512 slots

typedef short v8s __attribute__((ext_vector_type(8)));   // 8 bf16 in 4 VGPRs
typedef float f4v __attribute__((ext_vector_type(4)));   // mfma accumulator
typedef unsigned short ush;

__device__ __forceinline__ ush f2bf(float f) {
    unsigned int u = __float_as_uint(f);
    unsigned int r = (u + 0x7fffu + ((u >> 16) & 1u)) >> 16;   // RNE
    return (ush)r;
}
__device__ __forceinline__ float bf2f(ush h) {
    return __uint_as_float(((unsigned int)h) << 16);
}

// device-scope grid barrier, split-fence form.
// R2 lesson: ACQUIRE inside the poll loop emits a cache-invalidate PER POLL
// (buffer_inv each iteration from 360 blocks -> fabric saturation + cache
// thrash -> 805us). Fix: one release fence before arrive, RELAXED polls
// (plain coherent loads, no cache maintenance), one acquire fence on exit.
__device__ __forceinline__ void gbar(unsigned* c) {
    __syncthreads();
    if (threadIdx.x == 0) {
        __builtin_amdgcn_fence(__ATOMIC_RELEASE, "agent");   // publish our stores (once)
        __hip_atomic_fetch_add(c, 1u, __ATOMIC_RELAXED, __HIP_MEMORY_SCOPE_AGENT);
        while (__hip_atomic_load(c, __ATOMIC_RELAXED, __HIP_MEMORY_SCOPE_AGENT) < GRID) {
            __builtin_amdgcn_s_sleep(8);                     // ~512 clk backoff
        }
        __builtin_amdgcn_fence(__ATOMIC_ACQUIRE, "agent");   // see remote stores (once)
    }
    __syncthreads();
}

// One persistent kernel: prep -> 3x { sgemm -> reduce+squash -> mgemm }
// replaces 9 launches (8 device drain/ramp boundaries) with 8 in-kernel barriers.
__global__ __launch_bounds__(256, 2) void capsule_fused(
        const float* __restrict__ x, const float* __restrict__ W,
        float* __restrict__ v_out, float* __restrict__ ws) {
    // workspace layout: [0..63] barrier counters (+pad), then data
    unsigned* bar = (unsigned*)ws;                             // 8 used, 64 f reserved
    float* b_ij   = ws + 64;                                   // 11,520 f
    float* s_part = b_ij + ISZ * JJ;                           // 72*256*160 f
    ush* xsh = (ush*)(s_part + (size_t)NIC * BB * JD);         // [1152][2048]
    ush* xsl = xsh + (size_t)ISZ * 2048;
    ush* xth = xsl + (size_t)ISZ * 2048;                       // [9216][256]
    ush* xtl = xth + (size_t)K1 * BB;
    ush* vth = xtl + (size_t)K1 * BB;                          // [160][256]
    ush* vtl = vth + (size_t)JD * BB;

    const int bid  = blockIdx.x;
    const int t    = threadIdx.x;
    const int lane = t & 63, wv = t >> 6;
    const int col  = lane & 15, q = lane >> 4;

    // shared scratch, phase-aliased. max = prep's 32*8*65 floats = 66,560 B
    __shared__ __align__(16) char smem[66560];

    // ---------------- phase P: x[b,u,i] -> xs[i][b*8+u] + xt[u*1152+i][b]; b_ij=1 ----
    if (bid < 144) {
        float (*buf)[8][65] = (float (*)[8][65])smem;   // [32][8][65]
        int pit = bid % 18, bt = bid / 18;
        int i0 = pit * 64, b0 = bt * 32;
        int flat = bt * 18 + pit;
        if (flat < 45) b_ij[flat * 256 + t] = 1.0f;     // 45*256 = 11520

        for (int rep = 0; rep < 64; ++rep) {
            int row = rep * 4 + wv;                     // 0..255 = (bl,u)
            int bl = row >> 3, u = row & 7;
            buf[bl][u][lane] = x[(size_t)(b0 + bl) * K1 + (size_t)u * ISZ + i0 + lane];
        }
        __syncthreads();
        {   // xs[i][b*8+u]
            int bl = t >> 3, u = t & 7;
            for (int il = 0; il < 64; ++il) {
                float vv = buf[bl][u][il];
                ush h = f2bf(vv);
                size_t o = (size_t)(i0 + il) * 2048 + (size_t)(b0 + bl) * 8 + u;
                xsh[o] = h; xsl[o] = f2bf(vv - bf2f(h));
            }
        }
        {   // xt[u*1152+i][b]
            int g = t >> 5, bl = t & 31;
            for (int pass = 0; pass < 64; ++pass) {
                int cu = pass * 8 + g;
                int u = cu >> 6, il = cu & 63;
                float vv = buf[bl][u][il];
                ush h = f2bf(vv);
                size_t o = (size_t)(u * ISZ + i0 + il) * BB + b0 + bl;
                xth[o] = h; xtl[o] = f2bf(vv - bf2f(h));
            }
        }
    }
    gbar(&bar[0]);

    for (int it = 0; it < 3; ++it) {
        // ---------------- phase S: sgemm, block = (ic, jh) ----------------
        // bid = jh*72 + ic: the 5 blocks sharing an A-slice (same ic) are 72 apart
        // -> same XCD under round-robin -> A-slice L2-shared.
        {
            int ic = bid % NIC, jh = bid / NIC;
            int j0 = jh * 2, i0 = ic * ICH;

            ush (*bh_)[16][136] = (ush (*)[16][136])smem;            // [2][16][136] hi
            ush (*bl_)[16][136] = (ush (*)[16][136])(smem + 8704);   // lo
            float* c_lds = (float*)(smem + 17408);                   // [2][16]
            float* redm  = (float*)(smem + 17536);                   // [4]
            float* reds  = (float*)(smem + 17552);                   // [4]

            if (it == 0) {
                if (t < 2 * ICH) c_lds[t] = 1.0f / 1152.0f;
            } else {
                // parallel softmax: waves 0-1 -> jj=0, waves 2-3 -> jj=1
                int jj = wv >> 1, half = wv & 1;
                const float* bp = b_ij + (size_t)(j0 + jj) * ISZ;
                float m = -1e30f;
                for (int k = half * 64 + lane; k < ISZ; k += 128) m = fmaxf(m, bp[k]);
#pragma unroll
                for (int off = 32; off; off >>= 1) m = fmaxf(m, __shfl_down(m, off, 64));
                if (lane == 0) redm[wv] = m;
                __syncthreads();
                m = fmaxf(redm[jj * 2], redm[jj * 2 + 1]);
                float ssum = 0.f;
                for (int k = half * 64 + lane; k < ISZ; k += 128) ssum += __expf(bp[k] - m);
#pragma unroll
                for (int off = 32; off; off >>= 1) ssum += __shfl_down(ssum, off, 64);
                if (lane == 0) reds[wv] = ssum;
                __syncthreads();
                if (t < 2 * ICH) {
                    int cj = t >> 4, ci = t & 15;
                    float mj  = fmaxf(redm[cj * 2], redm[cj * 2 + 1]);
                    float inv = 1.f / (reds[cj * 2] + reds[cj * 2 + 1]);
                    c_lds[t] = __expf(b_ij[(size_t)(j0 + cj) * ISZ + i0 + ci] - mj) * inv;
                }
            }
            __syncthreads();

            // build B tiles: 512 slots = (jj, ii, d), 2 per thread
            for (int slot = t; slot < 512; slot += 256) {
                int jj = slot >> 8, rem = slot & 255, ii = rem >> 4, d = rem & 15;
                const float* wp = W + (size_t)(i0 + ii) * 1280 + (j0 + jj) * 128 + d * 8;
                float4 wa = *(const float4*)wp;
                float4 wb = *(const float4*)(wp + 4);
                float ci = c_lds[jj * 16 + ii];
                float vals[8] = { wa.x * ci, wa.y * ci, wa.z * ci, wa.w * ci,
                                  wb.x * ci, wb.y * ci, wb.z * ci, wb.w * ci };
                v8s hv, lv;
#pragma unroll
                for (int u = 0; u < 8; ++u) {
                    ush h = f2bf(vals[u]);
                    hv[u] = (short)h;
                    lv[u] = (short)f2bf(vals[u] - bf2f(h));
                }
                *(v8s*)&bh_[jj][d][ii * 8] = hv;
                *(v8s*)&bl_[jj][d][ii * 8] = lv;
            }
            __syncthreads();

            int m_base = wv * 64;
            f4v acc[4][2];
#pragma unroll
            for (int mm = 0; mm < 4; ++mm)
#pragma unroll
                for (int jj = 0; jj < 2; ++jj) acc[mm][jj] = (f4v){0.f, 0.f, 0.f, 0.f};

#pragma unroll
            for (int s = 0; s < 4; ++s) {           // 4 k-steps x 32 k = 128 k (16 i)
                v8s bh0 = *(const v8s*)&bh_[0][col][s * 32 + q * 8];
                v8s bl0 = *(const v8s*)&bl_[0][col][s * 32 + q * 8];
                v8s bh1 = *(const v8s*)&bh_[1][col][s * 32 + q * 8];
                v8s bl1 = *(const v8s*)&bl_[1][col][s * 32 + q * 8];
                size_t abase = (size_t)(i0 + s * 4 + q) * 2048;
#pragma unroll
                for (int mm = 0; mm < 4; ++mm) {
                    size_t ao = abase + (size_t)(m_base + mm * 16 + col) * 8;
                    v8s ah = *(const v8s*)(xsh + ao);
                    v8s al = *(const v8s*)(xsl + ao);
                    acc[mm][0] = __builtin_amdgcn_mfma_f32_16x16x32_bf16(ah, bh0, acc[mm][0], 0, 0, 0);
                    acc[mm][0] = __builtin_amdgcn_mfma_f32_16x16x32_bf16(ah, bl0, acc[mm][0], 0, 0, 0);
                    acc[mm][0] = __builtin_amdgcn_mfma_f32_16x16x32_bf16(al, bh0, acc[mm][0], 0, 0, 0);
                    acc[mm][1] = __builtin_amdgcn_mfma_f32_16x16x32_bf16(ah, bh1, acc[mm][1], 0, 0, 0);
                    acc[mm][1] = __builtin_amdgcn_mfma_f32_16x16x32_bf16(ah, bl1, acc[mm][1], 0, 0, 0);
                    acc[mm][1] = __builtin_amdgcn_mfma_f32_16x16x32_bf16(al, bh1, acc[mm][1], 0, 0, 0);
                }
            }
            // C/D: col = n, row = q*4+r (= b within m-tile)  [R7-verified]
#pragma unroll
            for (int mm = 0; mm < 4; ++mm)
#pragma unroll
                for (int jj = 0; jj < 2; ++jj)
#pragma unroll
                    for (int r = 0; r < 4; ++r)
                        s_part[((size_t)ic * BB + m_base + mm * 16 + q * 4 + r) * JD
                               + (j0 + jj) * DD + col] = acc[mm][jj][r];
        }
        gbar(&bar[1 + it * 3]);

        // ---------------- phase R: reduce split-K + squash ----------------
        if (bid < BB) {
            int b = bid;
            float* sm = (float*)smem;   // [JD]
            if (t < JD) {
                float s = 0.f;
#pragma unroll 8
                for (int p = 0; p < NIC; ++p) s += s_part[((size_t)p * BB + b) * JD + t];
                sm[t] = s;
            }
            __syncthreads();
            if (t < JD) {
                int d = t & 15;
                float msq = 0.f;
#pragma unroll
                for (int j = 0; j < JJ; ++j) { float xx = sm[j * DD + d]; msq += xx * xx; }
                float val = msq / (1.f + msq) * sm[t] * rsqrtf(msq);
                if (it == 2) {
                    v_out[(size_t)b * JD + t] = val;     // final output only
                } else {
                    ush h = f2bf(val);
                    vth[(size_t)t * BB + b] = h;
                    vtl[(size_t)t * BB + b] = f2bf(val - bf2f(h));
                }
            }
        }
        if (it == 2) return;   // uniform across the whole grid
        gbar(&bar[2 + it * 3]);

        // ---------------- phase M: mgemm + agreement epilogue [R7-verified] ----------
        {
            int wbase = bid * 4 + wv;       // 0..1439; 5760 wave-jobs -> 4 reps
#pragma unroll
            for (int rep = 0; rep < 4; ++rep) {
                int wj = wbase + rep * 1440;
                int mt = wj / 576, nt = wj % 576;
                int m0 = mt * 16, n0 = nt * 16;
                size_t aoff = (size_t)(m0 + col) * BB + q * 8;
                size_t boff = (size_t)(n0 + col) * BB + q * 8;
                f4v acc = {0.f, 0.f, 0.f, 0.f};
#pragma unroll
                for (int s = 0; s < BB / 32; ++s) {
                    v8s ah = *(const v8s*)(vth + aoff);
                    v8s al = *(const v8s*)(vtl + aoff);
                    v8s bh = *(const v8s*)(xth + boff);
                    v8s bl = *(const v8s*)(xtl + boff);
                    acc = __builtin_amdgcn_mfma_f32_16x16x32_bf16(ah, bh, acc, 0, 0, 0);
                    acc = __builtin_amdgcn_mfma_f32_16x16x32_bf16(ah, bl, acc, 0, 0, 0);
                    acc = __builtin_amdgcn_mfma_f32_16x16x32_bf16(al, bh, acc, 0, 0, 0);
                    aoff += 32; boff += 32;
                }
                int u = nt / 72;
                int i = (nt % 72) * 16 + col;
                const float* Wp = W + (size_t)i * 1280 + mt * 128 + q * 32 + u;
                float p = Wp[0] * acc[0] + Wp[8] * acc[1] + Wp[16] * acc[2] + Wp[24] * acc[3];
                p += __shfl_xor(p, 16, 64);
                p += __shfl_xor(p, 32, 64);
                if (q == 0) atomicAdd(&b_ij[(size_t)mt * ISZ + i], p * (1.0f / 256.0f));
            }
        }
        gbar(&bar[3 + it * 3]);
    }
}

extern "C" void kernel_launch(void* const* d_in, const int* in_sizes, int n_in,
                              void* d_out, int out_size, void* d_ws, size_t ws_size,
                              hipStream_t stream) {
    const float* x = (const float*)d_in[0];   // (256, 8, 1152)
    const float* W = (const float*)d_in[1];   // (1, 1152, 10, 16, 8)
    float* v_out = (float*)d_out;             // (256, 10, 16, 1)
    float* ws = (float*)d_ws;

    // zero the barrier counters (stream-ordered, graph-capture-safe)
    hipMemsetAsync(ws, 0, 64 * sizeof(float), stream);
    hipLaunchKernelGGL(capsule_fused, dim3(GRID), dim3(256), 0, stream,
                       x, W, v_out, ws);
}

// Round 4
// 388.347 us; speedup vs baseline: 2.0748x; 1.3924x over previous
//
#include <hip/hip_runtime.h>
#include <cstddef>

#define BB   256    // batch = GEMM1 M
#define UU   8      // in_units
#define ISZ  1152   // in_size
#define JJ   10     // out_units
#define DD   16     // out_size
#define JD   (JJ*DD)      // 160
#define K1   (UU*ISZ)     // 9216 ; sgemm k-order: k = i*8+u
#define ICH  16           // i per sgemm block
#define NIC  (ISZ/ICH)    // 72  (split-K part count)
#define NJH  5            // j-pairs
#define GRID (NIC*NJH)    // 360 blocks: 2/CU resident (LDS 66.6KB, VGPR 128)

#define ARRC 18           // arrival classes: 360/18 = 20 arrivals/line (parallel banks)
#define GOC  36           // go-flag lines: 10 pollers/line (no read queueing)
#define SYNCW 8448        // u32s reserved for sync area (33 KB)

typedef short v8s __attribute__((ext_vector_type(8)));   // 8 bf16 in 4 VGPRs
typedef float f4v __attribute__((ext_vector_type(4)));   // mfma accumulator
typedef unsigned short ush;

__device__ __forceinline__ ush f2bf(float f) {
    unsigned int u = __float_as_uint(f);
    unsigned int r = (u + 0x7fffu + ((u >> 16) & 1u)) >> 16;   // RNE
    return (ush)r;
}
__device__ __forceinline__ float bf2f(ush h) {
    return __uint_as_float(((unsigned int)h) << 16);
}

// Decontended device-scope grid barrier (R3 lesson: single-line arrivals+polls
// queue 25-50x over the LLC line service rate -> ~50us/barrier).
// Tree: 18 arrival lines (20 RMWs each, parallel) -> 1 level-2 line (18 RMWs)
// -> 36 go lines (10 pollers each, s_sleep-paced below line service rate).
// Causality: per-block fence(rel) before arrival RMW; leaders/setter bridge the
// relaxed RMW chain with acq/rel fence pairs; pollers fence(acq) on exit.
__device__ __forceinline__ void gbar(unsigned* sync, int epoch) {
    __syncthreads();
    if (threadIdx.x == 0) {
        unsigned* arr = sync;            // lines 0..17   (stride 64 u32 = 256 B)
        unsigned* l2  = sync + 4096;     // 1 line
        unsigned* go  = sync + 4352;     // lines 0..35
        int ac = blockIdx.x % ARRC, gc = blockIdx.x % GOC;
        __builtin_amdgcn_fence(__ATOMIC_RELEASE, "agent");   // publish our stores
        unsigned old = __hip_atomic_fetch_add(&arr[ac * 64], 1u,
                           __ATOMIC_RELAXED, __HIP_MEMORY_SCOPE_AGENT);
        if (old == (unsigned)(epoch * (GRID / ARRC) - 1)) {  // class leader
            __builtin_amdgcn_fence(__ATOMIC_ACQUIRE, "agent");
            __builtin_amdgcn_fence(__ATOMIC_RELEASE, "agent");
            unsigned o2 = __hip_atomic_fetch_add(l2, 1u,
                              __ATOMIC_RELAXED, __HIP_MEMORY_SCOPE_AGENT);
            if (o2 == (unsigned)(epoch * ARRC - 1)) {        // global last
                __builtin_amdgcn_fence(__ATOMIC_ACQUIRE, "agent");
                __builtin_amdgcn_fence(__ATOMIC_RELEASE, "agent");
                for (int g = 0; g < GOC; ++g)
                    __hip_atomic_store(&go[g * 64], (unsigned)epoch,
                                       __ATOMIC_RELAXED, __HIP_MEMORY_SCOPE_AGENT);
            }
        }
        while (__hip_atomic_load(&go[gc * 64], __ATOMIC_RELAXED,
                                 __HIP_MEMORY_SCOPE_AGENT) < (unsigned)epoch) {
            __builtin_amdgcn_s_sleep(32);                    // ~2048 clk
        }
        __builtin_amdgcn_fence(__ATOMIC_ACQUIRE, "agent");   // see remote stores
    }
    __syncthreads();
}

// One persistent kernel: prep -> 3x { sgemm -> reduce+squash -> mgemm }
__global__ __launch_bounds__(256, 2) void capsule_fused(
        const float* __restrict__ x, const float* __restrict__ W,
        float* __restrict__ v_out, float* __restrict__ ws) {
    // workspace layout: [0..SYNCW) barrier sync area, then data
    unsigned* sync = (unsigned*)ws;
    float* b_ij   = ws + SYNCW;                                // 11,520 f
    float* s_part = b_ij + ISZ * JJ;                           // 72*256*160 f
    ush* xsh = (ush*)(s_part + (size_t)NIC * BB * JD);         // [1152][2048]
    ush* xsl = xsh + (size_t)ISZ * 2048;
    ush* xth = xsl + (size_t)ISZ * 2048;                       // [9216][256]
    ush* xtl = xth + (size_t)K1 * BB;
    ush* vth = xtl + (size_t)K1 * BB;                          // [160][256]
    ush* vtl = vth + (size_t)JD * BB;

    const int bid  = blockIdx.x;
    const int t    = threadIdx.x;
    const int lane = t & 63, wv = t >> 6;
    const int col  = lane & 15, q = lane >> 4;

    // shared scratch, phase-aliased. max = prep's 32*8*65 floats = 66,560 B
    __shared__ __align__(16) char smem[66560];

    // ---------------- phase P: x[b,u,i] -> xs[i][b*8+u] + xt[u*1152+i][b]; b_ij=1 ----
    if (bid < 144) {
        float (*buf)[8][65] = (float (*)[8][65])smem;   // [32][8][65]
        int pit = bid % 18, bt = bid / 18;
        int i0 = pit * 64, b0 = bt * 32;
        int flat = bt * 18 + pit;
        if (flat < 45) b_ij[flat * 256 + t] = 1.0f;     // 45*256 = 11520

        for (int rep = 0; rep < 64; ++rep) {
            int row = rep * 4 + wv;                     // 0..255 = (bl,u)
            int bl = row >> 3, u = row & 7;
            buf[bl][u][lane] = x[(size_t)(b0 + bl) * K1 + (size_t)u * ISZ + i0 + lane];
        }
        __syncthreads();
        {   // xs[i][b*8+u]
            int bl = t >> 3, u = t & 7;
            for (int il = 0; il < 64; ++il) {
                float vv = buf[bl][u][il];
                ush h = f2bf(vv);
                size_t o = (size_t)(i0 + il) * 2048 + (size_t)(b0 + bl) * 8 + u;
                xsh[o] = h; xsl[o] = f2bf(vv - bf2f(h));
            }
        }
        {   // xt[u*1152+i][b]
            int g = t >> 5, bl = t & 31;
            for (int pass = 0; pass < 64; ++pass) {
                int cu = pass * 8 + g;
                int u = cu >> 6, il = cu & 63;
                float vv = buf[bl][u][il];
                ush h = f2bf(vv);
                size_t o = (size_t)(u * ISZ + i0 + il) * BB + b0 + bl;
                xth[o] = h; xtl[o] = f2bf(vv - bf2f(h));
            }
        }
    }
    gbar(sync, 1);

    for (int it = 0; it < 3; ++it) {
        // ---------------- phase S: sgemm, block = (ic, jh) ----------------
        // bid = jh*72 + ic: the 5 blocks sharing an A-slice (same ic) are 72 apart
        // -> same XCD under round-robin -> A-slice L2-shared.
        {
            int ic = bid % NIC, jh = bid / NIC;
            int j0 = jh * 2, i0 = ic * ICH;

            ush (*bh_)[16][136] = (ush (*)[16][136])smem;            // [2][16][136] hi
            ush (*bl_)[16][136] = (ush (*)[16][136])(smem + 8704);   // lo
            float* c_lds = (float*)(smem + 17408);                   // [2][16]
            float* redm  = (float*)(smem + 17536);                   // [4]
            float* reds  = (float*)(smem + 17552);                   // [4]

            if (it == 0) {
                if (t < 2 * ICH) c_lds[t] = 1.0f / 1152.0f;
            } else {
                // parallel softmax: waves 0-1 -> jj=0, waves 2-3 -> jj=1
                int jj = wv >> 1, half = wv & 1;
                const float* bp = b_ij + (size_t)(j0 + jj) * ISZ;
                float m = -1e30f;
                for (int k = half * 64 + lane; k < ISZ; k += 128) m = fmaxf(m, bp[k]);
#pragma unroll
                for (int off = 32; off; off >>= 1) m = fmaxf(m, __shfl_down(m, off, 64));
                if (lane == 0) redm[wv] = m;
                __syncthreads();
                m = fmaxf(redm[jj * 2], redm[jj * 2 + 1]);
                float ssum = 0.f;
                for (int k = half * 64 + lane; k < ISZ; k += 128) ssum += __expf(bp[k] - m);
#pragma unroll
                for (int off = 32; off; off >>= 1) ssum += __shfl_down(ssum, off, 64);
                if (lane == 0) reds[wv] = ssum;
                __syncthreads();
                if (t < 2 * ICH) {
                    int cj = t >> 4, ci = t & 15;
                    float mj  = fmaxf(redm[cj * 2], redm[cj * 2 + 1]);
                    float inv = 1.f / (reds[cj * 2] + reds[cj * 2 + 1]);
                    c_lds[t] = __expf(b_ij[(size_t)(j0 + cj) * ISZ + i0 + ci] - mj) * inv;
                }
            }
            __syncthreads();

            // build B tiles: 512 slots = (jj, ii, d), 2 per thread
            for (int slot = t; slot < 512; slot += 256) {
                int jj = slot >> 8, rem = slot & 255, ii = rem >> 4, d = rem & 15;
                const float* wp = W + (size_t)(i0 + ii) * 1280 + (j0 + jj) * 128 + d * 8;
                float4 wa = *(const float4*)wp;
                float4 wb = *(const float4*)(wp + 4);
                float ci = c_lds[jj * 16 + ii];
                float vals[8] = { wa.x * ci, wa.y * ci, wa.z * ci, wa.w * ci,
                                  wb.x * ci, wb.y * ci, wb.z * ci, wb.w * ci };
                v8s hv, lv;
#pragma unroll
                for (int u = 0; u < 8; ++u) {
                    ush h = f2bf(vals[u]);
                    hv[u] = (short)h;
                    lv[u] = (short)f2bf(vals[u] - bf2f(h));
                }
                *(v8s*)&bh_[jj][d][ii * 8] = hv;
                *(v8s*)&bl_[jj][d][ii * 8] = lv;
            }
            __syncthreads();

            int m_base = wv * 64;
            f4v acc[4][2];
#pragma unroll
            for (int mm = 0; mm < 4; ++mm)
#pragma unroll
                for (int jj = 0; jj < 2; ++jj) acc[mm][jj] = (f4v){0.f, 0.f, 0.f, 0.f};

#pragma unroll
            for (int s = 0; s < 4; ++s) {           // 4 k-steps x 32 k = 128 k (16 i)
                v8s bh0 = *(const v8s*)&bh_[0][col][s * 32 + q * 8];
                v8s bl0 = *(const v8s*)&bl_[0][col][s * 32 + q * 8];
                v8s bh1 = *(const v8s*)&bh_[1][col][s * 32 + q * 8];
                v8s bl1 = *(const v8s*)&bl_[1][col][s * 32 + q * 8];
                size_t abase = (size_t)(i0 + s * 4 + q) * 2048;
#pragma unroll
                for (int mm = 0; mm < 4; ++mm) {
                    size_t ao = abase + (size_t)(m_base + mm * 16 + col) * 8;
                    v8s ah = *(const v8s*)(xsh + ao);
                    v8s al = *(const v8s*)(xsl + ao);
                    acc[mm][0] = __builtin_amdgcn_mfma_f32_16x16x32_bf16(ah, bh0, acc[mm][0], 0, 0, 0);
                    acc[mm][0] = __builtin_amdgcn_mfma_f32_16x16x32_bf16(ah, bl0, acc[mm][0], 0, 0, 0);
                    acc[mm][0] = __builtin_amdgcn_mfma_f32_16x16x32_bf16(al, bh0, acc[mm][0], 0, 0, 0);
                    acc[mm][1] = __builtin_amdgcn_mfma_f32_16x16x32_bf16(ah, bh1, acc[mm][1], 0, 0, 0);
                    acc[mm][1] = __builtin_amdgcn_mfma_f32_16x16x32_bf16(ah, bl1, acc[mm][1], 0, 0, 0);
                    acc[mm][1] = __builtin_amdgcn_mfma_f32_16x16x32_bf16(al, bh1, acc[mm][1], 0, 0, 0);
                }
            }
            // C/D: col = n, row = q*4+r (= b within m-tile)  [R7-verified]
#pragma unroll
            for (int mm = 0; mm < 4; ++mm)
#pragma unroll
                for (int jj = 0; jj < 2; ++jj)
#pragma unroll
                    for (int r = 0; r < 4; ++r)
                        s_part[((size_t)ic * BB + m_base + mm * 16 + q * 4 + r) * JD
                               + (j0 + jj) * DD + col] = acc[mm][jj][r];
        }
        gbar(sync, 2 + it * 3);

        // ---------------- phase R: reduce split-K + squash ----------------
        if (bid < BB) {
            int b = bid;
            float* sm = (float*)smem;   // [JD]
            if (t < JD) {
                float s = 0.f;
#pragma unroll 8
                for (int p = 0; p < NIC; ++p) s += s_part[((size_t)p * BB + b) * JD + t];
                sm[t] = s;
            }
            __syncthreads();
            if (t < JD) {
                int d = t & 15;
                float msq = 0.f;
#pragma unroll
                for (int j = 0; j < JJ; ++j) { float xx = sm[j * DD + d]; msq += xx * xx; }
                float val = msq / (1.f + msq) * sm[t] * rsqrtf(msq);
                if (it == 2) {
                    v_out[(size_t)b * JD + t] = val;     // final output only
                } else {
                    ush h = f2bf(val);
                    vth[(size_t)t * BB + b] = h;
                    vtl[(size_t)t * BB + b] = f2bf(val - bf2f(h));
                }
            }
        }
        if (it == 2) return;   // uniform across the whole grid
        gbar(sync, 3 + it * 3);

        // ---------------- phase M: mgemm + agreement epilogue [R7-verified] ----------
        {
            int wbase = bid * 4 + wv;       // 0..1439; 5760 wave-jobs -> 4 reps
#pragma unroll
            for (int rep = 0; rep < 4; ++rep) {
                int wj = wbase + rep * 1440;
                int mt = wj / 576, nt = wj % 576;
                int m0 = mt * 16, n0 = nt * 16;
                size_t aoff = (size_t)(m0 + col) * BB + q * 8;
                size_t boff = (size_t)(n0 + col) * BB + q * 8;
                f4v acc = {0.f, 0.f, 0.f, 0.f};
#pragma unroll
                for (int s = 0; s < BB / 32; ++s) {
                    v8s ah = *(const v8s*)(vth + aoff);
                    v8s al = *(const v8s*)(vtl + aoff);
                    v8s bh = *(const v8s*)(xth + boff);
                    v8s bl = *(const v8s*)(xtl + boff);
                    acc = __builtin_amdgcn_mfma_f32_16x16x32_bf16(ah, bh, acc, 0, 0, 0);
                    acc = __builtin_amdgcn_mfma_f32_16x16x32_bf16(ah, bl, acc, 0, 0, 0);
                    acc = __builtin_amdgcn_mfma_f32_16x16x32_bf16(al, bh, acc, 0, 0, 0);
                    aoff += 32; boff += 32;
                }
                int u = nt / 72;
                int i = (nt % 72) * 16 + col;
                const float* Wp = W + (size_t)i * 1280 + mt * 128 + q * 32 + u;
                float p = Wp[0] * acc[0] + Wp[8] * acc[1] + Wp[16] * acc[2] + Wp[24] * acc[3];
                p += __shfl_xor(p, 16, 64);
                p += __shfl_xor(p, 32, 64);
                if (q == 0) atomicAdd(&b_ij[(size_t)mt * ISZ + i], p * (1.0f / 256.0f));
            }
        }
        gbar(sync, 4 + it * 3);
    }
}

extern "C" void kernel_launch(void* const* d_in, const int* in_sizes, int n_in,
                              void* d_out, int out_size, void* d_ws, size_t ws_size,
                              hipStream_t stream) {
    const float* x = (const float*)d_in[0];   // (256, 8, 1152)
    const float* W = (const float*)d_in[1];   // (1, 1152, 10, 16, 8)
    float* v_out = (float*)d_out;             // (256, 10, 16, 1)
    float* ws = (float*)d_ws;

    // zero the barrier sync area (stream-ordered, graph-capture-safe)
    hipMemsetAsync(ws, 0, SYNCW * sizeof(float), stream);
    hipLaunchKernelGGL(capsule_fused, dim3(GRID), dim3(256), 0, stream,
                       x, W, v_out, ws);
}

// Round 5
// 292.139 us; speedup vs baseline: 2.7581x; 1.3293x over previous
//
#include <hip/hip_runtime.h>
#include <cstddef>

#define BB   256    // batch = GEMM1 M
#define UU   8      // in_units
#define ISZ  1152   // in_size
#define JJ   10     // out_units
#define DD   16     // out_size
#define JD   (JJ*DD)      // 160
#define K1   (UU*ISZ)     // 9216 ; sgemm k-order: k = i*8+u
#define ICH  16           // i per sgemm block
#define NIC  (ISZ/ICH)    // 72  (split-K part count)
#define NJH  5            // j-pairs
#define GRID (NIC*NJH)    // 360 blocks: 2/CU resident (LDS 66.6KB, VGPR<=256)

#define ARRC 18           // arrival classes: 360/18 = 20 arrivals/line
#define GOC  36           // go-flag lines: 10 pollers/line
#define SYNCW 8448        // u32s reserved for sync area (33 KB)

typedef short v8s __attribute__((ext_vector_type(8)));   // 8 bf16 in 4 VGPRs
typedef float f4v __attribute__((ext_vector_type(4)));   // mfma accumulator
typedef unsigned short ush;

__device__ __forceinline__ ush f2bf(float f) {
    unsigned int u = __float_as_uint(f);
    unsigned int r = (u + 0x7fffu + ((u >> 16) & 1u)) >> 16;   // RNE
    return (ush)r;
}
__device__ __forceinline__ float bf2f(ush h) {
    return __uint_as_float(((unsigned int)h) << 16);
}

// LLC-coherent (agent-scope) stores: write through past the non-coherent
// per-XCD L2 to the device-coherent LLC. Cross-phase intermediates are
// written ONLY through these, so grid barriers need NO cache fences.
__device__ __forceinline__ void st_dword_sc1(float* p, float v) {
    asm volatile("global_store_dword %0, %1, off sc0 sc1" :: "v"(p), "v"(v) : "memory");
}
__device__ __forceinline__ void st_short_sc1(ush* p, ush v) {
    asm volatile("global_store_short %0, %1, off sc0 sc1" :: "v"(p), "v"((unsigned)v) : "memory");
}

// Fence-free device-scope grid barrier (R4 tree topology kept).
// R4 lesson: per-block fence(rel/acq, agent) = 720 full-L2 wb/inv ops per
// barrier (~33us) AND cold caches every phase. Here: data path is coherent
// by construction (sc1 stores / sc1-or-versioned reads), so the barrier
// only needs completion (vmcnt drain, all waves -- compiler does NOT track
// inline-asm stores, so __syncthreads alone is insufficient) + ordering
// through LLC atomics. No wbl2, no inv: W/xs/xt stay L2-hot across phases.
__device__ __forceinline__ void gbar(unsigned* sync, int epoch) {
    asm volatile("s_waitcnt vmcnt(0)" ::: "memory");   // drain this wave's sc1 stores
    __syncthreads();
    if (threadIdx.x == 0) {
        unsigned* arr = sync;            // lines 0..17 (stride 64 u32 = 256 B)
        unsigned* l2  = sync + 4096;     // 1 line
        unsigned* go  = sync + 4352;     // lines 0..35
        int ac = blockIdx.x % ARRC, gc = blockIdx.x % GOC;
        unsigned old = __hip_atomic_fetch_add(&arr[ac * 64], 1u,
                           __ATOMIC_RELAXED, __HIP_MEMORY_SCOPE_AGENT);
        if (old == (unsigned)(epoch * (GRID / ARRC) - 1)) {  // class leader
            unsigned o2 = __hip_atomic_fetch_add(l2, 1u,
                              __ATOMIC_RELAXED, __HIP_MEMORY_SCOPE_AGENT);
            if (o2 == (unsigned)(epoch * ARRC - 1)) {        // global last
                for (int g = 0; g < GOC; ++g)
                    __hip_atomic_store(&go[g * 64], (unsigned)epoch,
                                       __ATOMIC_RELAXED, __HIP_MEMORY_SCOPE_AGENT);
            }
        }
        while (__hip_atomic_load(&go[gc * 64], __ATOMIC_RELAXED,
                                 __HIP_MEMORY_SCOPE_AGENT) < (unsigned)epoch) {
            __builtin_amdgcn_s_sleep(8);
        }
    }
    __syncthreads();
}

// Coherence audit (why no fences are needed):
//  xs/xt : sc1-written once (prep), normal cached reads later (never rewritten)
//  b_ij  : sc1 init; LLC atomics (mgemm); sc1 reads (softmax) -- no L2 copies ever
//  s_part: sc1 stores (sgemm), sc1 reads (reduce) -- no L2 copies ever
//  vth/vtl: sc1 stores (reduce), iteration-parity versioned buffers -> mgemm's
//           normal cached reads always first-touch fresh addresses
//  v_out : normal stores, published by kernel-end release
__global__ __launch_bounds__(256, 2) void capsule_fused(
        const float* __restrict__ x, const float* __restrict__ W,
        float* __restrict__ v_out, float* __restrict__ ws) {
    unsigned* sync = (unsigned*)ws;
    float* b_ij   = ws + SYNCW;                                // 11,520 f
    float* s_part = b_ij + ISZ * JJ;                           // 72*256*160 f
    ush* xsh = (ush*)(s_part + (size_t)NIC * BB * JD);         // [1152][2048]
    ush* xsl = xsh + (size_t)ISZ * 2048;
    ush* xth = xsl + (size_t)ISZ * 2048;                       // [9216][256]
    ush* xtl = xth + (size_t)K1 * BB;
    ush* vth = xtl + (size_t)K1 * BB;                          // [2][160*256]
    ush* vtl = vth + 2 * (size_t)JD * BB;                      // [2][160*256]

    const int bid  = blockIdx.x;
    const int t    = threadIdx.x;
    const int lane = t & 63, wv = t >> 6;
    const int col  = lane & 15, q = lane >> 4;

    __shared__ __align__(16) char smem[66560];

    // ---------------- phase P: x[b,u,i] -> xs[i][b*8+u] + xt[u*1152+i][b]; b_ij=1 ----
    if (bid < 144) {
        float (*buf)[8][65] = (float (*)[8][65])smem;   // [32][8][65]
        int pit = bid % 18, bt = bid / 18;
        int i0 = pit * 64, b0 = bt * 32;
        int flat = bt * 18 + pit;
        if (flat < 45) st_dword_sc1(&b_ij[flat * 256 + t], 1.0f);   // 45*256 = 11520

        for (int rep = 0; rep < 64; ++rep) {
            int row = rep * 4 + wv;                     // 0..255 = (bl,u)
            int bl = row >> 3, u = row & 7;
            buf[bl][u][lane] = x[(size_t)(b0 + bl) * K1 + (size_t)u * ISZ + i0 + lane];
        }
        __syncthreads();
        {   // xs[i][b*8+u]
            int bl = t >> 3, u = t & 7;
            for (int il = 0; il < 64; ++il) {
                float vv = buf[bl][u][il];
                ush h = f2bf(vv);
                size_t o = (size_t)(i0 + il) * 2048 + (size_t)(b0 + bl) * 8 + u;
                st_short_sc1(xsh + o, h);
                st_short_sc1(xsl + o, f2bf(vv - bf2f(h)));
            }
        }
        {   // xt[u*1152+i][b]
            int g = t >> 5, bl = t & 31;
            for (int pass = 0; pass < 64; ++pass) {
                int cu = pass * 8 + g;
                int u = cu >> 6, il = cu & 63;
                float vv = buf[bl][u][il];
                ush h = f2bf(vv);
                size_t o = (size_t)(u * ISZ + i0 + il) * BB + b0 + bl;
                st_short_sc1(xth + o, h);
                st_short_sc1(xtl + o, f2bf(vv - bf2f(h)));
            }
        }
    }
    gbar(sync, 1);

    for (int it = 0; it < 3; ++it) {
        // ---------------- phase S: sgemm, block = (ic, jh) ----------------
        {
            int ic = bid % NIC, jh = bid / NIC;
            int j0 = jh * 2, i0 = ic * ICH;

            ush (*bh_)[16][136] = (ush (*)[16][136])smem;            // [2][16][136] hi
            ush (*bl_)[16][136] = (ush (*)[16][136])(smem + 8704);   // lo
            float* c_lds = (float*)(smem + 17408);                   // [2][16]
            float* redm  = (float*)(smem + 17536);                   // [4]
            float* reds  = (float*)(smem + 17552);                   // [4]

            if (it == 0) {
                if (t < 2 * ICH) c_lds[t] = 1.0f / 1152.0f;
            } else {
                // parallel softmax over b_ij (sc1 reads: b_ij lives at LLC only)
                int jj = wv >> 1, half = wv & 1;
                const float* bp = b_ij + (size_t)(j0 + jj) * ISZ + half * 64 + lane;
                float v9[9];                      // 1152/128 = 9 strided values
#pragma unroll
                for (int k = 0; k < 9; ++k)
                    asm volatile("global_load_dword %0, %1, off sc0 sc1"
                                 : "=v"(v9[k]) : "v"(bp + k * 128));
                asm volatile("s_waitcnt vmcnt(0)" ::: "memory");
                __builtin_amdgcn_sched_barrier(0);    // rule 18: pin consumers after wait
                float m = -1e30f;
#pragma unroll
                for (int k = 0; k < 9; ++k) m = fmaxf(m, v9[k]);
#pragma unroll
                for (int off = 32; off; off >>= 1) m = fmaxf(m, __shfl_down(m, off, 64));
                if (lane == 0) redm[wv] = m;
                __syncthreads();
                m = fmaxf(redm[jj * 2], redm[jj * 2 + 1]);
                float ssum = 0.f;
#pragma unroll
                for (int k = 0; k < 9; ++k) ssum += __expf(v9[k] - m);
#pragma unroll
                for (int off = 32; off; off >>= 1) ssum += __shfl_down(ssum, off, 64);
                if (lane == 0) reds[wv] = ssum;
                __syncthreads();
                if (t < 2 * ICH) {
                    int cj = t >> 4, ci = t & 15;
                    float mj  = fmaxf(redm[cj * 2], redm[cj * 2 + 1]);
                    float inv = 1.f / (reds[cj * 2] + reds[cj * 2 + 1]);
                    float bv;
                    asm volatile("global_load_dword %0, %1, off sc0 sc1\n\ts_waitcnt vmcnt(0)"
                                 : "=v"(bv)
                                 : "v"(b_ij + (size_t)(j0 + cj) * ISZ + i0 + ci));
                    c_lds[t] = __expf(bv - mj) * inv;
                }
            }
            __syncthreads();

            // build B tiles: 512 slots = (jj, ii, d), 2 per thread (W: normal, L2-hot)
            for (int slot = t; slot < 512; slot += 256) {
                int jj = slot >> 8, rem = slot & 255, ii = rem >> 4, d = rem & 15;
                const float* wp = W + (size_t)(i0 + ii) * 1280 + (j0 + jj) * 128 + d * 8;
                float4 wa = *(const float4*)wp;
                float4 wb = *(const float4*)(wp + 4);
                float ci = c_lds[jj * 16 + ii];
                float vals[8] = { wa.x * ci, wa.y * ci, wa.z * ci, wa.w * ci,
                                  wb.x * ci, wb.y * ci, wb.z * ci, wb.w * ci };
                v8s hv, lv;
#pragma unroll
                for (int u = 0; u < 8; ++u) {
                    ush h = f2bf(vals[u]);
                    hv[u] = (short)h;
                    lv[u] = (short)f2bf(vals[u] - bf2f(h));
                }
                *(v8s*)&bh_[jj][d][ii * 8] = hv;
                *(v8s*)&bl_[jj][d][ii * 8] = lv;
            }
            __syncthreads();

            int m_base = wv * 64;
            f4v acc[4][2];
#pragma unroll
            for (int mm = 0; mm < 4; ++mm)
#pragma unroll
                for (int jj = 0; jj < 2; ++jj) acc[mm][jj] = (f4v){0.f, 0.f, 0.f, 0.f};

#pragma unroll
            for (int s = 0; s < 4; ++s) {           // 4 k-steps x 32 k = 128 k (16 i)
                v8s bh0 = *(const v8s*)&bh_[0][col][s * 32 + q * 8];
                v8s bl0 = *(const v8s*)&bl_[0][col][s * 32 + q * 8];
                v8s bh1 = *(const v8s*)&bh_[1][col][s * 32 + q * 8];
                v8s bl1 = *(const v8s*)&bl_[1][col][s * 32 + q * 8];
                size_t abase = (size_t)(i0 + s * 4 + q) * 2048;
#pragma unroll
                for (int mm = 0; mm < 4; ++mm) {
                    size_t ao = abase + (size_t)(m_base + mm * 16 + col) * 8;
                    v8s ah = *(const v8s*)(xsh + ao);     // normal: write-once, L2-hot
                    v8s al = *(const v8s*)(xsl + ao);
                    acc[mm][0] = __builtin_amdgcn_mfma_f32_16x16x32_bf16(ah, bh0, acc[mm][0], 0, 0, 0);
                    acc[mm][0] = __builtin_amdgcn_mfma_f32_16x16x32_bf16(ah, bl0, acc[mm][0], 0, 0, 0);
                    acc[mm][0] = __builtin_amdgcn_mfma_f32_16x16x32_bf16(al, bh0, acc[mm][0], 0, 0, 0);
                    acc[mm][1] = __builtin_amdgcn_mfma_f32_16x16x32_bf16(ah, bh1, acc[mm][1], 0, 0, 0);
                    acc[mm][1] = __builtin_amdgcn_mfma_f32_16x16x32_bf16(ah, bl1, acc[mm][1], 0, 0, 0);
                    acc[mm][1] = __builtin_amdgcn_mfma_f32_16x16x32_bf16(al, bh1, acc[mm][1], 0, 0, 0);
                }
            }
            // C/D: col = n, row = q*4+r  [R7-verified]; sc1 stores -> LLC
#pragma unroll
            for (int mm = 0; mm < 4; ++mm)
#pragma unroll
                for (int jj = 0; jj < 2; ++jj)
#pragma unroll
                    for (int r = 0; r < 4; ++r)
                        st_dword_sc1(&s_part[((size_t)ic * BB + m_base + mm * 16 + q * 4 + r) * JD
                                             + (j0 + jj) * DD + col], acc[mm][jj][r]);
        }
        gbar(sync, 2 + it * 3);

        // ---------------- phase R: reduce split-K + squash ----------------
        if (bid < BB) {
            int b = bid;
            float* sm = (float*)smem;   // [JD]
            if (t < JD) {
                const float* sp0 = s_part + (size_t)b * JD + t;
                float s = 0.f;
                float tmp[12];
#pragma unroll
                for (int c = 0; c < 6; ++c) {          // 72 parts = 6 chunks x 12
#pragma unroll
                    for (int u = 0; u < 12; ++u)
                        asm volatile("global_load_dword %0, %1, off sc0 sc1"
                                     : "=v"(tmp[u])
                                     : "v"(sp0 + (size_t)(c * 12 + u) * (BB * JD)));
                    asm volatile("s_waitcnt vmcnt(0)" ::: "memory");
                    __builtin_amdgcn_sched_barrier(0);  // rule 18
#pragma unroll
                    for (int u = 0; u < 12; ++u) s += tmp[u];
                }
                sm[t] = s;
            }
            __syncthreads();
            if (t < JD) {
                int d = t & 15;
                float msq = 0.f;
#pragma unroll
                for (int j = 0; j < JJ; ++j) { float xx = sm[j * DD + d]; msq += xx * xx; }
                float val = msq / (1.f + msq) * sm[t] * rsqrtf(msq);
                if (it == 2) {
                    v_out[(size_t)b * JD + t] = val;     // final output only
                } else {
                    ush* vh = vth + (size_t)(it & 1) * (JD * BB);  // iteration-versioned
                    ush* vl = vtl + (size_t)(it & 1) * (JD * BB);
                    ush h = f2bf(val);
                    st_short_sc1(&vh[(size_t)t * BB + b], h);
                    st_short_sc1(&vl[(size_t)t * BB + b], f2bf(val - bf2f(h)));
                }
            }
        }
        if (it == 2) return;   // uniform across the whole grid
        gbar(sync, 3 + it * 3);

        // ---------------- phase M: mgemm + agreement epilogue [R7-verified] ----------
        {
            const ush* Avh = vth + (size_t)(it & 1) * (JD * BB);   // versioned, normal reads
            const ush* Avl = vtl + (size_t)(it & 1) * (JD * BB);
            int wbase = bid * 4 + wv;       // 0..1439; 5760 wave-jobs -> 4 reps
#pragma unroll
            for (int rep = 0; rep < 4; ++rep) {
                int wj = wbase + rep * 1440;
                int mt = wj / 576, nt = wj % 576;
                int m0 = mt * 16, n0 = nt * 16;
                size_t aoff = (size_t)(m0 + col) * BB + q * 8;
                size_t boff = (size_t)(n0 + col) * BB + q * 8;
                f4v acc = {0.f, 0.f, 0.f, 0.f};
#pragma unroll
                for (int s = 0; s < BB / 32; ++s) {
                    v8s ah = *(const v8s*)(Avh + aoff);
                    v8s al = *(const v8s*)(Avl + aoff);
                    v8s bh = *(const v8s*)(xth + boff);   // normal: write-once, L2-hot
                    v8s bl = *(const v8s*)(xtl + boff);
                    acc = __builtin_amdgcn_mfma_f32_16x16x32_bf16(ah, bh, acc, 0, 0, 0);
                    acc = __builtin_amdgcn_mfma_f32_16x16x32_bf16(ah, bl, acc, 0, 0, 0);
                    acc = __builtin_amdgcn_mfma_f32_16x16x32_bf16(al, bh, acc, 0, 0, 0);
                    aoff += 32; boff += 32;
                }
                int u = nt / 72;
                int i = (nt % 72) * 16 + col;
                const float* Wp = W + (size_t)i * 1280 + mt * 128 + q * 32 + u;
                float p = Wp[0] * acc[0] + Wp[8] * acc[1] + Wp[16] * acc[2] + Wp[24] * acc[3];
                p += __shfl_xor(p, 16, 64);
                p += __shfl_xor(p, 32, 64);
                if (q == 0) atomicAdd(&b_ij[(size_t)mt * ISZ + i], p * (1.0f / 256.0f));
            }
        }
        gbar(sync, 4 + it * 3);
    }
}

extern "C" void kernel_launch(void* const* d_in, const int* in_sizes, int n_in,
                              void* d_out, int out_size, void* d_ws, size_t ws_size,
                              hipStream_t stream) {
    const float* x = (const float*)d_in[0];   // (256, 8, 1152)
    const float* W = (const float*)d_in[1];   // (1, 1152, 10, 16, 8)
    float* v_out = (float*)d_out;             // (256, 10, 16, 1)
    float* ws = (float*)d_ws;

    // zero the barrier sync area (stream-ordered, graph-capture-safe)
    hipMemsetAsync(ws, 0, SYNCW * sizeof(float), stream);
    hipLaunchKernelGGL(capsule_fused, dim3(GRID), dim3(256), 0, stream,
                       x, W, v_out, ws);
}

// Round 6
// 180.703 us; speedup vs baseline: 4.4590x; 1.6167x over previous
//
#include <hip/hip_runtime.h>
#include <cstddef>

#define BB   256    // batch = GEMM1 M
#define UU   8      // in_units
#define ISZ  1152   // in_size
#define JJ   10     // out_units
#define DD   16     // out_size
#define JD   (JJ*DD)      // 160
#define K1   (UU*ISZ)     // 9216 ; sgemm k-order: k = i*8+u
#define ICH  16           // i per sgemm block
#define NIC  (ISZ/ICH)    // 72  (split-K part count)
#define NJH  5            // j-pairs

typedef short v8s __attribute__((ext_vector_type(8)));   // 8 bf16 in 4 VGPRs
typedef float f4v __attribute__((ext_vector_type(4)));   // mfma accumulator
typedef unsigned short ush;

__device__ __forceinline__ ush f2bf(float f) {
    unsigned int u = __float_as_uint(f);
    unsigned int r = (u + 0x7fffu + ((u >> 16) & 1u)) >> 16;   // RNE
    return (ush)r;
}
__device__ __forceinline__ float bf2f(ush h) {
    return __uint_as_float(((unsigned int)h) << 16);
}

// ---------------- prep: x[b,u,i] -> xs[i][b*8+u] (split) + xt[u*1152+i][b] (split); b_ij=1 ----
__global__ void prep_kernel(const float* __restrict__ x,
                            ush* __restrict__ xsh, ush* __restrict__ xsl,
                            ush* __restrict__ xth, ush* __restrict__ xtl,
                            float* __restrict__ b_ij, unsigned* __restrict__ done) {
    __shared__ float buf[32][8][65];
    int it = blockIdx.x;            // 18 tiles of 64 i
    int bt = blockIdx.y;            // 8 tiles of 32 b
    int i0 = it * 64, b0 = bt * 32;
    int t = threadIdx.x, lane = t & 63, wv = t >> 6;

    int flat = bt * 18 + it;
    if (flat < 45) b_ij[flat * 256 + t] = 1.0f;   // 45*256 = 11520
    if (flat == 0 && t < 16) done[t] = 0;         // mgemm last-block counters

    for (int rep = 0; rep < 64; ++rep) {
        int row = rep * 4 + wv;     // 0..255 = (bl,u)
        int bl = row >> 3, u = row & 7;
        buf[bl][u][lane] = x[(size_t)(b0 + bl) * K1 + (size_t)u * ISZ + i0 + lane];
    }
    __syncthreads();
    {   // xs[i][b*8+u]
        int bl = t >> 3, u = t & 7;
        for (int il = 0; il < 64; ++il) {
            float v = buf[bl][u][il];
            ush h = f2bf(v);
            size_t o = (size_t)(i0 + il) * 2048 + (size_t)(b0 + bl) * 8 + u;
            xsh[o] = h; xsl[o] = f2bf(v - bf2f(h));
        }
    }
    {   // xt[u*1152+i][b]
        int g = t >> 5, bl = t & 31;
        for (int pass = 0; pass < 64; ++pass) {
            int cu = pass * 8 + g;
            int u = cu >> 6, il = cu & 63;
            float v = buf[bl][u][il];
            ush h = f2bf(v);
            size_t o = (size_t)(u * ISZ + i0 + il) * BB + b0 + bl;
            xth[o] = h; xtl[o] = f2bf(v - bf2f(h));
        }
    }
}

// ---------------- sgemm: s_part[b][ic][jd] for 2 j x 16 i per block ----------------
// grid (NIC, NJH) = (72, 5): the 5 blocks sharing an A-slice (same ic) are 72 apart
// -> same XCD -> A-slice L2-shared. c_ij comes precomputed from c_tab (mgemm's
// last block) -- no per-block softmax (R6: removes 2x1152 reduction from 360 blocks).
__global__ __launch_bounds__(256, 2) void sgemm_fused(
        const ush* __restrict__ xsh, const ush* __restrict__ xsl,
        const float* __restrict__ W, const float* __restrict__ c_tab,
        float* __restrict__ s_part, int it) {
    int ic = blockIdx.x, jh = blockIdx.y;
    int j0 = jh * 2, i0 = ic * ICH;
    int t = threadIdx.x, lane = t & 63, wv = t >> 6;
    int col = lane & 15, q = lane >> 4;

    __shared__ __align__(16) ush bh_[2][16][136];   // B^T hi [jj][d][k_local]
    __shared__ __align__(16) ush bl_[2][16][136];   // B^T lo
    __shared__ float c_lds[2][ICH];

    if (t < 2 * ICH) {
        int cj = t >> 4, ci = t & 15;
        c_lds[cj][ci] = (it == 0) ? (1.0f / 1152.0f)
                                  : c_tab[(size_t)(j0 + cj) * ISZ + i0 + ci];
    }
    __syncthreads();

    // build B tiles: 512 slots = (jj, ii, d), 2 per thread
    for (int slot = t; slot < 512; slot += 256) {
        int jj = slot >> 8, rem = slot & 255, ii = rem >> 4, d = rem & 15;
        const float* wp = W + (size_t)(i0 + ii) * 1280 + (j0 + jj) * 128 + d * 8;
        float4 wa = *(const float4*)wp;
        float4 wb = *(const float4*)(wp + 4);
        float ci = c_lds[jj][ii];
        float vals[8] = { wa.x * ci, wa.y * ci, wa.z * ci, wa.w * ci,
                          wb.x * ci, wb.y * ci, wb.z * ci, wb.w * ci };
        v8s hv, lv;
#pragma unroll
        for (int u = 0; u < 8; ++u) {
            ush h = f2bf(vals[u]);
            hv[u] = (short)h;
            lv[u] = (short)f2bf(vals[u] - bf2f(h));
        }
        *(v8s*)&bh_[jj][d][ii * 8] = hv;
        *(v8s*)&bl_[jj][d][ii * 8] = lv;
    }
    __syncthreads();

    int m_base = wv * 64;
    f4v acc[4][2];
#pragma unroll
    for (int mm = 0; mm < 4; ++mm)
#pragma unroll
        for (int jj = 0; jj < 2; ++jj) acc[mm][jj] = (f4v){0.f, 0.f, 0.f, 0.f};

#pragma unroll
    for (int s = 0; s < 4; ++s) {           // 4 k-steps x 32 k = 128 k (16 i)
        v8s bh0 = *(const v8s*)&bh_[0][col][s * 32 + q * 8];
        v8s bl0 = *(const v8s*)&bl_[0][col][s * 32 + q * 8];
        v8s bh1 = *(const v8s*)&bh_[1][col][s * 32 + q * 8];
        v8s bl1 = *(const v8s*)&bl_[1][col][s * 32 + q * 8];
        size_t abase = (size_t)(i0 + s * 4 + q) * 2048;
#pragma unroll
        for (int mm = 0; mm < 4; ++mm) {
            size_t ao = abase + (size_t)(m_base + mm * 16 + col) * 8;
            v8s ah = *(const v8s*)(xsh + ao);
            v8s al = *(const v8s*)(xsl + ao);
            acc[mm][0] = __builtin_amdgcn_mfma_f32_16x16x32_bf16(ah, bh0, acc[mm][0], 0, 0, 0);
            acc[mm][0] = __builtin_amdgcn_mfma_f32_16x16x32_bf16(ah, bl0, acc[mm][0], 0, 0, 0);
            acc[mm][0] = __builtin_amdgcn_mfma_f32_16x16x32_bf16(al, bh0, acc[mm][0], 0, 0, 0);
            acc[mm][1] = __builtin_amdgcn_mfma_f32_16x16x32_bf16(ah, bh1, acc[mm][1], 0, 0, 0);
            acc[mm][1] = __builtin_amdgcn_mfma_f32_16x16x32_bf16(ah, bl1, acc[mm][1], 0, 0, 0);
            acc[mm][1] = __builtin_amdgcn_mfma_f32_16x16x32_bf16(al, bh1, acc[mm][1], 0, 0, 0);
        }
    }
    // C/D: col = n, row = q*4+r (= b within m-tile)  [R7-verified]
    // R6: s_part transposed to [b][ic][jd] -> reduce reads contiguous 46KB/block
#pragma unroll
    for (int mm = 0; mm < 4; ++mm)
#pragma unroll
        for (int jj = 0; jj < 2; ++jj)
#pragma unroll
            for (int r = 0; r < 4; ++r)
                s_part[((size_t)(m_base + mm * 16 + q * 4 + r) * NIC + ic) * JD
                       + (j0 + jj) * DD + col] = acc[mm][jj][r];
}

// ---------------- reduce split-K + squash; v_out, vT bf16-split ----------------
__global__ void reduce_squash(const float* __restrict__ s_part, float* __restrict__ v,
                              ush* __restrict__ vth, ush* __restrict__ vtl) {
    int b = blockIdx.x, t = threadIdx.x;   // 192, t<160 active
    __shared__ float sm[JD];
    if (t < JD) {
        const float* sp = s_part + (size_t)b * NIC * JD + t;   // contiguous 46KB region
        float s = 0.f;
#pragma unroll 8
        for (int p = 0; p < NIC; ++p) s += sp[(size_t)p * JD];
        sm[t] = s;
    }
    __syncthreads();
    if (t < JD) {
        int d = t & 15;
        float msq = 0.f;
#pragma unroll
        for (int j = 0; j < JJ; ++j) { float xx = sm[j * DD + d]; msq += xx * xx; }
        float val = msq / (1.f + msq) * sm[t] * rsqrtf(msq);
        v[(size_t)b * JD + t] = val;
        ush h = f2bf(val);
        vth[(size_t)t * BB + b] = h;
        vtl[(size_t)t * BB + b] = f2bf(val - bf2f(h));
    }
}

// ---------------- mgemm + agreement epilogue [R7-verified] ----------------
// R6 remap: wave w -> mt = w/288, jobs (mt, 2*(w%288)+{0,1}): same-mt pairs give
// A-fragment L1 reuse + adjacent-nt B locality (was wj+2880 scatter).
// Last finished block (done-counter at LLC; b_ij only touched by LLC atomics in
// this kernel -> its fresh reads see all updates) computes c_tab = softmax(b_ij)
// for the next iteration's sgemm.
__global__ __launch_bounds__(256) void mgemm_agree(
        const ush* __restrict__ Ah, const ush* __restrict__ Al,
        const ush* __restrict__ Bh, const ush* __restrict__ Bl,
        const float* __restrict__ W, float* __restrict__ b_ij,
        float* __restrict__ c_tab, unsigned* __restrict__ done, int it) {
    int wv = threadIdx.x >> 6, lane = threadIdx.x & 63;
    int col = lane & 15, q = lane >> 4;
    int w = blockIdx.x * 4 + wv;        // 720 blocks -> waves 0..2879
    int mt = w / 288, nt2 = w % 288;
    int m0 = mt * 16;
#pragma unroll
    for (int rep = 0; rep < 2; ++rep) {
        int nt = nt2 * 2 + rep;
        int n0 = nt * 16;
        size_t aoff = (size_t)(m0 + col) * BB + q * 8;   // same both reps -> L1 hit
        size_t boff = (size_t)(n0 + col) * BB + q * 8;
        f4v acc = {0.f, 0.f, 0.f, 0.f};
#pragma unroll
        for (int s = 0; s < BB / 32; ++s) {
            v8s ah = *(const v8s*)(Ah + aoff);
            v8s al = *(const v8s*)(Al + aoff);
            v8s bh = *(const v8s*)(Bh + boff);
            v8s bl = *(const v8s*)(Bl + boff);
            acc = __builtin_amdgcn_mfma_f32_16x16x32_bf16(ah, bh, acc, 0, 0, 0);
            acc = __builtin_amdgcn_mfma_f32_16x16x32_bf16(ah, bl, acc, 0, 0, 0);
            acc = __builtin_amdgcn_mfma_f32_16x16x32_bf16(al, bh, acc, 0, 0, 0);
            aoff += 32; boff += 32;
        }
        int u = nt / 72;
        int i = (nt % 72) * 16 + col;
        const float* Wp = W + (size_t)i * 1280 + mt * 128 + q * 32 + u;
        float p = Wp[0] * acc[0] + Wp[8] * acc[1] + Wp[16] * acc[2] + Wp[24] * acc[3];
        p += __shfl_xor(p, 16, 64);
        p += __shfl_xor(p, 32, 64);
        if (q == 0) atomicAdd(&b_ij[(size_t)mt * ISZ + i], p * (1.0f / 256.0f));
    }

    // ---- last-block softmax precompute: c_tab[j][i] = softmax_i(b_ij[j][i]) ----
    __shared__ unsigned lastf;
    asm volatile("s_waitcnt vmcnt(0)" ::: "memory");   // our atomics complete at LLC
    __syncthreads();
    if (threadIdx.x == 0) {
        unsigned old = __hip_atomic_fetch_add(&done[it], 1u,
                           __ATOMIC_RELAXED, __HIP_MEMORY_SCOPE_AGENT);
        lastf = (old == 719u);
    }
    __syncthreads();
    if (lastf) {
        for (int j = wv; j < JJ; j += 4) {            // wave wv: j = wv, wv+4, wv+8
            const float* bp = b_ij + (size_t)j * ISZ;
            float vals[18];
#pragma unroll
            for (int k = 0; k < 18; ++k) vals[k] = bp[lane + 64 * k];
            float m = -1e30f;
#pragma unroll
            for (int k = 0; k < 18; ++k) m = fmaxf(m, vals[k]);
#pragma unroll
            for (int off = 32; off; off >>= 1) m = fmaxf(m, __shfl_xor(m, off, 64));
            float ssum = 0.f;
#pragma unroll
            for (int k = 0; k < 18; ++k) ssum += __expf(vals[k] - m);
#pragma unroll
            for (int off = 32; off; off >>= 1) ssum += __shfl_xor(ssum, off, 64);
            float inv = 1.f / ssum;
#pragma unroll
            for (int k = 0; k < 18; ++k)
                c_tab[(size_t)j * ISZ + lane + 64 * k] = __expf(vals[k] - m) * inv;
        }
    }
}

extern "C" void kernel_launch(void* const* d_in, const int* in_sizes, int n_in,
                              void* d_out, int out_size, void* d_ws, size_t ws_size,
                              hipStream_t stream) {
    const float* x = (const float*)d_in[0];   // (256, 8, 1152)
    const float* W = (const float*)d_in[1];   // (1, 1152, 10, 16, 8)
    float* v_out = (float*)d_out;             // (256, 10, 16, 1)

    float* b_ij  = (float*)d_ws;                           // 11,520 f
    float* c_tab = b_ij + ISZ * JJ;                        // 11,520 f
    float* dptr  = c_tab + ISZ * JJ;
    unsigned* done = (unsigned*)dptr;                      // 64 u32 (16 used)
    float* s_part = dptr + 64;                             // 256*72*160 f (transposed)
    ush* xsh = (ush*)(s_part + (size_t)BB * NIC * JD);     // [1152][2048]
    ush* xsl = xsh + (size_t)ISZ * 2048;
    ush* xth = xsl + (size_t)ISZ * 2048;                   // [9216][256]
    ush* xtl = xth + (size_t)K1 * BB;
    ush* vth = xtl + (size_t)K1 * BB;                      // [160][256]
    ush* vtl = vth + (size_t)JD * BB;

    hipLaunchKernelGGL(prep_kernel, dim3(18, 8), dim3(256), 0, stream,
                       x, xsh, xsl, xth, xtl, b_ij, done);
    for (int it = 0; it < 3; ++it) {
        hipLaunchKernelGGL(sgemm_fused, dim3(NIC, NJH), dim3(256), 0, stream,
                           xsh, xsl, W, c_tab, s_part, it);
        hipLaunchKernelGGL(reduce_squash, dim3(BB), dim3(192), 0, stream,
                           s_part, v_out, vth, vtl);
        if (it < 2) {
            hipLaunchKernelGGL(mgemm_agree, dim3(720), dim3(256), 0, stream,
                               vth, vtl, xth, xtl, W, b_ij, c_tab, done, it);
        }
    }
}